// Round 1
// baseline (54.015 us; speedup 1.0000x reference)
//
#include <hip/hip_runtime.h>

#define CROP   28
#define NBOX   100
#define IMG_H  512
#define IMG_W  512
#define IMG_C  32
#define BATCH  8

// One thread handles one (box, oy, ox, c4) where c4 indexes a float4 group of
// 4 channels. 8 consecutive threads cover one output pixel's 32 channels ->
// each corner gather is a contiguous, 128B-aligned 128-byte read.
__global__ __launch_bounds__(256) void crop_resize_kernel(
    const float* __restrict__ images,
    const float* __restrict__ boxes,
    float* __restrict__ out)
{
    const int tid = blockIdx.x * blockDim.x + threadIdx.x;
    const int total = BATCH * NBOX * CROP * CROP * (IMG_C / 4);
    if (tid >= total) return;

    const int c4 = tid & 7;        // float4 group within channel dim
    const int p  = tid >> 3;       // pixel id: n*784 + y*28 + x
    const int x  = p % CROP;
    const int t  = p / CROP;
    const int y  = t % CROP;
    const int n  = t / CROP;       // box id 0..799
    const int b  = n / NBOX;       // batch image index

    const float by1 = boxes[n * 4 + 0];
    const float bx1 = boxes[n * 4 + 1];
    const float by2 = boxes[n * 4 + 2];
    const float bx2 = boxes[n * 4 + 3];

    const float Hm1 = (float)(IMG_H - 1);
    const float Wm1 = (float)(IMG_W - 1);
    const float h_scale = (by2 - by1) * Hm1 / (float)(CROP - 1);
    const float w_scale = (bx2 - bx1) * Wm1 / (float)(CROP - 1);

    const float in_y = by1 * Hm1 + (float)y * h_scale;
    const float in_x = bx1 * Wm1 + (float)x * w_scale;

    const bool valid = (in_y >= 0.0f) && (in_y <= Hm1) &&
                       (in_x >= 0.0f) && (in_x <= Wm1);

    const float y0f = floorf(in_y);
    const float x0f = floorf(in_x);
    const float ly = in_y - y0f;
    const float lx = in_x - x0f;

    int y0 = (int)y0f; y0 = y0 < 0 ? 0 : (y0 > IMG_H - 1 ? IMG_H - 1 : y0);
    int x0 = (int)x0f; x0 = x0 < 0 ? 0 : (x0 > IMG_W - 1 ? IMG_W - 1 : x0);
    const int y1i = (y0 + 1 < IMG_H - 1) ? y0 + 1 : IMG_H - 1;
    const int x1i = (x0 + 1 < IMG_W - 1) ? x0 + 1 : IMG_W - 1;

    const int C4 = IMG_C / 4;                 // 8 float4 per pixel
    const float4* img4 = (const float4*)images;

    const int rowStride = IMG_W * C4;         // float4 units per image row
    const int imgStride = IMG_H * rowStride;  // float4 units per image
    const int base = b * imgStride;
    const int r0 = base + y0  * rowStride;
    const int r1 = base + y1i * rowStride;

    const float4 tl = img4[r0 + x0  * C4 + c4];
    const float4 tr = img4[r0 + x1i * C4 + c4];
    const float4 bl = img4[r1 + x0  * C4 + c4];
    const float4 br = img4[r1 + x1i * C4 + c4];

    float4 res;
    {
        const float topx = tl.x + (tr.x - tl.x) * lx;
        const float botx = bl.x + (br.x - bl.x) * lx;
        res.x = topx + (botx - topx) * ly;
        const float topy = tl.y + (tr.y - tl.y) * lx;
        const float boty = bl.y + (br.y - bl.y) * lx;
        res.y = topy + (boty - topy) * ly;
        const float topz = tl.z + (tr.z - tl.z) * lx;
        const float botz = bl.z + (br.z - bl.z) * lx;
        res.z = topz + (botz - topz) * ly;
        const float topw = tl.w + (tr.w - tl.w) * lx;
        const float botw = bl.w + (br.w - bl.w) * lx;
        res.w = topw + (botw - topw) * ly;
    }

    if (!valid) {
        res.x = 0.0f; res.y = 0.0f; res.z = 0.0f; res.w = 0.0f;
    }

    ((float4*)out)[p * C4 + c4] = res;
}

extern "C" void kernel_launch(void* const* d_in, const int* in_sizes, int n_in,
                              void* d_out, int out_size, void* d_ws, size_t ws_size,
                              hipStream_t stream) {
    const float* images = (const float*)d_in[0];
    const float* boxes  = (const float*)d_in[1];
    float* out = (float*)d_out;

    const int total = BATCH * NBOX * CROP * CROP * (IMG_C / 4); // 5,017,600
    const int block = 256;
    const int grid = (total + block - 1) / block;               // 19,600
    crop_resize_kernel<<<grid, block, 0, stream>>>(images, boxes, out);
}

// Round 3
// 53.422 us; speedup vs baseline: 1.0111x; 1.0111x over previous
//
#include <hip/hip_runtime.h>

#define CROP   28
#define NBOX   100
#define IMG_H  512
#define IMG_W  512
#define IMG_C  32
#define BATCH  8

// Native clang vector type: __builtin_nontemporal_store requires a vector of
// scalars, not HIP's struct-wrapped float4.
typedef float floatx4 __attribute__((ext_vector_type(4)));

// One thread handles one (box, oy, ox, c4) where c4 indexes a float4 group of
// 4 channels. 8 consecutive threads cover one output pixel's 32 channels ->
// each corner gather is a contiguous, 128B-aligned 128-byte read.
// Output stores are nontemporal: write-once data must not evict image lines
// from L2/LLC (image = 256 MB ~= LLC capacity; repeat corner fetches rely on
// LLC hits).
__global__ __launch_bounds__(256) void crop_resize_kernel(
    const float* __restrict__ images,
    const float* __restrict__ boxes,
    float* __restrict__ out)
{
    const int tid = blockIdx.x * blockDim.x + threadIdx.x;
    const int total = BATCH * NBOX * CROP * CROP * (IMG_C / 4);
    if (tid >= total) return;

    const int c4 = tid & 7;        // float4 group within channel dim
    const int p  = tid >> 3;       // pixel id: n*784 + y*28 + x
    const int x  = p % CROP;
    const int t  = p / CROP;
    const int y  = t % CROP;
    const int n  = t / CROP;       // box id 0..799
    const int b  = n / NBOX;       // batch image index

    const float by1 = boxes[n * 4 + 0];
    const float bx1 = boxes[n * 4 + 1];
    const float by2 = boxes[n * 4 + 2];
    const float bx2 = boxes[n * 4 + 3];

    const float Hm1 = (float)(IMG_H - 1);
    const float Wm1 = (float)(IMG_W - 1);
    const float h_scale = (by2 - by1) * Hm1 / (float)(CROP - 1);
    const float w_scale = (bx2 - bx1) * Wm1 / (float)(CROP - 1);

    const float in_y = by1 * Hm1 + (float)y * h_scale;
    const float in_x = bx1 * Wm1 + (float)x * w_scale;

    const bool valid = (in_y >= 0.0f) && (in_y <= Hm1) &&
                       (in_x >= 0.0f) && (in_x <= Wm1);

    const float y0f = floorf(in_y);
    const float x0f = floorf(in_x);
    const float ly = in_y - y0f;
    const float lx = in_x - x0f;

    int y0 = (int)y0f; y0 = y0 < 0 ? 0 : (y0 > IMG_H - 1 ? IMG_H - 1 : y0);
    int x0 = (int)x0f; x0 = x0 < 0 ? 0 : (x0 > IMG_W - 1 ? IMG_W - 1 : x0);
    const int y1i = (y0 + 1 < IMG_H - 1) ? y0 + 1 : IMG_H - 1;
    const int x1i = (x0 + 1 < IMG_W - 1) ? x0 + 1 : IMG_W - 1;

    const int C4 = IMG_C / 4;                 // 8 float4 per pixel
    const floatx4* img4 = (const floatx4*)images;

    const int rowStride = IMG_W * C4;         // float4 units per image row
    const int imgStride = IMG_H * rowStride;  // float4 units per image
    const int base = b * imgStride;
    const int r0 = base + y0  * rowStride;
    const int r1 = base + y1i * rowStride;

    const floatx4 tl = img4[r0 + x0  * C4 + c4];
    const floatx4 tr = img4[r0 + x1i * C4 + c4];
    const floatx4 bl = img4[r1 + x0  * C4 + c4];
    const floatx4 br = img4[r1 + x1i * C4 + c4];

    const floatx4 top = tl + (tr - tl) * lx;
    const floatx4 bot = bl + (br - bl) * lx;
    floatx4 res = top + (bot - top) * ly;

    if (!valid) {
        res = (floatx4)0.0f;
    }

    floatx4* dst = ((floatx4*)out) + p * C4 + c4;
    __builtin_nontemporal_store(res, dst);
}

extern "C" void kernel_launch(void* const* d_in, const int* in_sizes, int n_in,
                              void* d_out, int out_size, void* d_ws, size_t ws_size,
                              hipStream_t stream) {
    const float* images = (const float*)d_in[0];
    const float* boxes  = (const float*)d_in[1];
    float* out = (float*)d_out;

    const int total = BATCH * NBOX * CROP * CROP * (IMG_C / 4); // 5,017,600
    const int block = 256;
    const int grid = (total + block - 1) / block;               // 19,600
    crop_resize_kernel<<<grid, block, 0, stream>>>(images, boxes, out);
}

// Round 4
// 51.961 us; speedup vs baseline: 1.0395x; 1.0281x over previous
//
#include <hip/hip_runtime.h>

#define CROP   28
#define NBOX   100
#define IMG_H  512
#define IMG_W  512
#define IMG_C  32
#define BATCH  8

typedef float floatx4 __attribute__((ext_vector_type(4)));

// One thread per (pixel, q) with q in 0..3. Thread q handles float4 groups
// {q, q+4} of the 8 per pixel (byte offsets q*16 and 64+q*16): two dwordx4
// loads per corner (second folds to offset:64), 8 independent gather loads in
// flight per thread. 4 consecutive lanes cover a contiguous 64B per
// instruction; 16 pixels per wave. Half the waves / address math of the
// 1-float4-per-thread version, double the MLP.
__global__ __launch_bounds__(256) void crop_resize_kernel(
    const float* __restrict__ images,
    const float* __restrict__ boxes,
    float* __restrict__ out)
{
    const int tid = blockIdx.x * blockDim.x + threadIdx.x;
    const int total = BATCH * NBOX * CROP * CROP * 4;
    if (tid >= total) return;

    const int q  = tid & 3;        // quarter-of-line index
    const int p  = tid >> 2;       // pixel id: n*784 + y*28 + x
    const int x  = p % CROP;
    const int t  = p / CROP;
    const int y  = t % CROP;
    const int n  = t / CROP;       // box id 0..799
    const int b  = n / NBOX;       // batch image index

    const float by1 = boxes[n * 4 + 0];
    const float bx1 = boxes[n * 4 + 1];
    const float by2 = boxes[n * 4 + 2];
    const float bx2 = boxes[n * 4 + 3];

    const float Hm1 = (float)(IMG_H - 1);
    const float Wm1 = (float)(IMG_W - 1);
    const float h_scale = (by2 - by1) * Hm1 / (float)(CROP - 1);
    const float w_scale = (bx2 - bx1) * Wm1 / (float)(CROP - 1);

    const float in_y = by1 * Hm1 + (float)y * h_scale;
    const float in_x = bx1 * Wm1 + (float)x * w_scale;

    const bool valid = (in_y >= 0.0f) && (in_y <= Hm1) &&
                       (in_x >= 0.0f) && (in_x <= Wm1);

    const float y0f = floorf(in_y);
    const float x0f = floorf(in_x);
    const float ly = in_y - y0f;
    const float lx = in_x - x0f;

    int y0 = (int)y0f; y0 = y0 < 0 ? 0 : (y0 > IMG_H - 1 ? IMG_H - 1 : y0);
    int x0 = (int)x0f; x0 = x0 < 0 ? 0 : (x0 > IMG_W - 1 ? IMG_W - 1 : x0);
    const int y1i = (y0 + 1 < IMG_H - 1) ? y0 + 1 : IMG_H - 1;
    const int x1i = (x0 + 1 < IMG_W - 1) ? x0 + 1 : IMG_W - 1;

    const int C4 = IMG_C / 4;                 // 8 float4 per pixel
    const floatx4* img4 = (const floatx4*)images;

    const int rowStride = IMG_W * C4;         // float4 units per image row
    const int imgStride = IMG_H * rowStride;  // float4 units per image
    const int base = b * imgStride;
    const int r0 = base + y0  * rowStride;
    const int r1 = base + y1i * rowStride;

    // float4-unit base addresses of the 4 corner pixels, plus this thread's
    // quarter offset. Second load of each corner is +4 float4s (offset:64).
    const int atl = r0 + x0  * C4 + q;
    const int atr = r0 + x1i * C4 + q;
    const int abl = r1 + x0  * C4 + q;
    const int abr = r1 + x1i * C4 + q;

    const floatx4 tl0 = img4[atl];
    const floatx4 tl1 = img4[atl + 4];
    const floatx4 tr0 = img4[atr];
    const floatx4 tr1 = img4[atr + 4];
    const floatx4 bl0 = img4[abl];
    const floatx4 bl1 = img4[abl + 4];
    const floatx4 br0 = img4[abr];
    const floatx4 br1 = img4[abr + 4];

    const floatx4 top0 = tl0 + (tr0 - tl0) * lx;
    const floatx4 bot0 = bl0 + (br0 - bl0) * lx;
    floatx4 res0 = top0 + (bot0 - top0) * ly;

    const floatx4 top1 = tl1 + (tr1 - tl1) * lx;
    const floatx4 bot1 = bl1 + (br1 - bl1) * lx;
    floatx4 res1 = top1 + (bot1 - top1) * ly;

    if (!valid) {
        res0 = (floatx4)0.0f;
        res1 = (floatx4)0.0f;
    }

    floatx4* dst = ((floatx4*)out) + p * C4 + q;
    __builtin_nontemporal_store(res0, dst);
    __builtin_nontemporal_store(res1, dst + 4);
}

extern "C" void kernel_launch(void* const* d_in, const int* in_sizes, int n_in,
                              void* d_out, int out_size, void* d_ws, size_t ws_size,
                              hipStream_t stream) {
    const float* images = (const float*)d_in[0];
    const float* boxes  = (const float*)d_in[1];
    float* out = (float*)d_out;

    const int total = BATCH * NBOX * CROP * CROP * 4; // 2,508,800
    const int block = 256;
    const int grid = (total + block - 1) / block;     // 9,800
    crop_resize_kernel<<<grid, block, 0, stream>>>(images, boxes, out);
}